// Round 1
// baseline (45129.691 us; speedup 1.0000x reference)
//
#include <hip/hip_runtime.h>
#include <math.h>

#define BATCH 32
#define SEQ   512
#define IDIM  256
#define RDIM  2048
#define ODIM  256
#define LEAK  0.3f

#define SCAN_BLOCKS  256
#define SCAN_THREADS 512
#define ROWS_PER_BLK 8   // RDIM / SCAN_BLOCKS

// ---------------------------------------------------------------------------
// init: copy initial state into states slot 0, zero barrier vars
// ---------------------------------------------------------------------------
__global__ void esn_init(const float* __restrict__ s0, float* __restrict__ states,
                         unsigned* __restrict__ bar_cnt, unsigned* __restrict__ bar_sns) {
    int idx = blockIdx.x * blockDim.x + threadIdx.x;
    const int n4 = (BATCH * RDIM) / 4;
    if (idx < n4) {
        ((float4*)states)[idx] = ((const float4*)s0)[idx];
    }
    if (idx == 0) { *bar_cnt = 0u; *bar_sns = 0u; }
}

// ---------------------------------------------------------------------------
// persistent cooperative scan kernel
// grid 256 x 512. Block owns rows [r0, r0+8) of W, resident in LDS.
// wave w handles batches 4w..4w+3; lane: bb = lane&3, ks = lane>>2 (16 k-slices)
// thread's k set: k = 4*ks + 64*i, i = 0..31  (and i-dim for u_proj: 4*ks + 64*j, j<4)
// ---------------------------------------------------------------------------
__global__ __launch_bounds__(SCAN_THREADS) void esn_scan(
    const float* __restrict__ u,      // (B, T, I)
    const float* __restrict__ Win,    // (R, I)
    const float* __restrict__ W,      // (R, R)
    const float* __restrict__ bias,   // (R)
    float* __restrict__ states,       // (T+1, B, R) workspace
    unsigned* __restrict__ bar_cnt,
    unsigned* __restrict__ bar_sns)
{
    __shared__ float Wl[ROWS_PER_BLK * RDIM];   // 64 KB

    const int tid  = threadIdx.x;
    const int bid  = blockIdx.x;
    const int r0   = bid * ROWS_PER_BLK;

    // ---- stage W slice (contiguous 64 KB) into LDS ----
    {
        const float4* src = (const float4*)(W + (size_t)r0 * RDIM);
        float4* dst = (float4*)Wl;
        #pragma unroll
        for (int idx = 0; idx < (ROWS_PER_BLK * RDIM) / 4 / SCAN_THREADS; ++idx)
            dst[idx * SCAN_THREADS + tid] = src[idx * SCAN_THREADS + tid];
    }

    const int wave = tid >> 6;
    const int lane = tid & 63;
    const int bb   = lane & 3;
    const int ks   = lane >> 2;          // 0..15
    const int b    = wave * 4 + bb;      // 0..31
    const int k0   = ks * 4;             // 0..60

    // finalize-lane constants (lanes 0..31 active): pair (bf, rr)
    float my_bias = 0.0f;
    if (lane < 32) my_bias = bias[r0 + (lane >> 2)];
    const int bf = wave * 4 + (lane & 3);

    float acc[8];

    // u_proj partial for one timestep (accumulates into acc, Win read from L1/L2)
    auto u_part = [&](int t) {
        const float* ub = u + ((size_t)b * SEQ + t) * IDIM;
        #pragma unroll
        for (int j = 0; j < 4; ++j) {
            const int iu = k0 + 64 * j;
            float4 u4 = *(const float4*)(ub + iu);
            #pragma unroll
            for (int r = 0; r < 8; ++r) {
                float4 w4 = *(const float4*)(Win + (size_t)(r0 + r) * IDIM + iu);
                acc[r] += w4.x * u4.x + w4.y * u4.y + w4.z * u4.z + w4.w * u4.w;
            }
        }
    };

    __syncthreads();   // Wl ready

    #pragma unroll
    for (int r = 0; r < 8; ++r) acc[r] = 0.0f;
    u_part(0);

    unsigned phase = 0;

    for (int t = 0; t < SEQ; ++t) {
        const float* prev = states + (size_t)t * BATCH * RDIM;
        float* next = states + (size_t)(t + 1) * BATCH * RDIM;

        // ---- main recurrent dot: acc[r] += sum_k s[b][k] * W[r0+r][k] ----
        const float* sp = prev + (size_t)b * RDIM + k0;
        #pragma unroll 4
        for (int i = 0; i < 32; ++i) {
            float4 s4 = *(const float4*)(sp + 64 * i);
            #pragma unroll
            for (int r = 0; r < 8; ++r) {
                float4 w4 = *(const float4*)(&Wl[r * RDIM + k0 + 64 * i]);
                acc[r] += w4.x * s4.x + w4.y * s4.y + w4.z * s4.z + w4.w * s4.w;
            }
        }

        // ---- reduce over the 16 k-slices (xor 4,8,16,32 keeps bb class) ----
        #pragma unroll
        for (int m = 4; m <= 32; m <<= 1) {
            #pragma unroll
            for (int r = 0; r < 8; ++r) acc[r] += __shfl_xor(acc[r], m, 64);
        }

        // ---- finalize: lanes 0..31 handle (bf, rr) ----
        if (lane < 32) {
            const int rr = lane >> 2;
            float pre = acc[0];
            #pragma unroll
            for (int r = 1; r < 8; ++r) if (rr == r) pre = acc[r];
            pre += my_bias;
            float so = prev[(size_t)bf * RDIM + r0 + rr];
            float sn = (1.0f - LEAK) * so + LEAK * tanhf(pre);
            next[(size_t)bf * RDIM + r0 + rr] = sn;
        }

        // ---- grid barrier (arrive early, overlap u_proj(t+1) with the wait) ----
        ++phase;
        __threadfence();
        __syncthreads();
        if (tid == 0) {
            unsigned old = __hip_atomic_fetch_add(bar_cnt, 1u, __ATOMIC_ACQ_REL,
                                                  __HIP_MEMORY_SCOPE_AGENT);
            if (old == phase * (unsigned)SCAN_BLOCKS - 1u) {
                __hip_atomic_store(bar_sns, phase, __ATOMIC_RELEASE,
                                   __HIP_MEMORY_SCOPE_AGENT);
            }
        }
        // independent work while the barrier propagates
        #pragma unroll
        for (int r = 0; r < 8; ++r) acc[r] = 0.0f;
        if (t + 1 < SEQ) u_part(t + 1);
        if (tid == 0) {
            while (__hip_atomic_load(bar_sns, __ATOMIC_ACQUIRE,
                                     __HIP_MEMORY_SCOPE_AGENT) < phase) {
                __builtin_amdgcn_s_sleep(1);
            }
        }
        __syncthreads();
        __threadfence();   // acquire side: don't read stale state
    }
}

// ---------------------------------------------------------------------------
// readout: out[b][t][o] = sum_r states[t+1][b][r] * w_ro[o][r] + b_ro[o]
// 64 rows x 64 outs per block, k-tile 32, transposed LDS tiles
// ---------------------------------------------------------------------------
#define RO_THREADS 256
__global__ __launch_bounds__(RO_THREADS) void esn_readout(
    const float* __restrict__ states,   // (T+1, B, R); rows (t*32+b) start at slot 1
    const float* __restrict__ w_ro,     // (O, R)
    const float* __restrict__ b_ro,     // (O)
    float* __restrict__ out)            // (B, T, O)
{
    __shared__ float St[32][68];
    __shared__ float Wt[32][68];

    const int tid  = threadIdx.x;
    const int rb   = blockIdx.x >> 2;
    const int ob   = blockIdx.x & 3;
    const int row0 = rb * 64;
    const int o0   = ob * 64;
    const float* S = states + (size_t)BATCH * RDIM;   // skip slot 0

    const int lr = tid >> 3;          // 0..31
    const int lk = (tid & 7) * 4;     // 0..28
    const int tx = tid & 15;          // o quad
    const int ty = tid >> 4;          // row quad

    float acc[4][4] = {};

    for (int kt = 0; kt < RDIM; kt += 32) {
        float4 a0 = *(const float4*)(S + (size_t)(row0 + lr)      * RDIM + kt + lk);
        float4 a1 = *(const float4*)(S + (size_t)(row0 + 32 + lr) * RDIM + kt + lk);
        float4 w0 = *(const float4*)(w_ro + (size_t)(o0 + lr)      * RDIM + kt + lk);
        float4 w1 = *(const float4*)(w_ro + (size_t)(o0 + 32 + lr) * RDIM + kt + lk);
        __syncthreads();
        float av0[4] = {a0.x, a0.y, a0.z, a0.w};
        float av1[4] = {a1.x, a1.y, a1.z, a1.w};
        float wv0[4] = {w0.x, w0.y, w0.z, w0.w};
        float wv1[4] = {w1.x, w1.y, w1.z, w1.w};
        #pragma unroll
        for (int j = 0; j < 4; ++j) {
            St[lk + j][lr]      = av0[j];
            St[lk + j][32 + lr] = av1[j];
            Wt[lk + j][lr]      = wv0[j];
            Wt[lk + j][32 + lr] = wv1[j];
        }
        __syncthreads();
        #pragma unroll
        for (int k = 0; k < 32; ++k) {
            float4 a4 = *(const float4*)(&St[k][4 * ty]);
            float4 b4 = *(const float4*)(&Wt[k][4 * tx]);
            float av[4] = {a4.x, a4.y, a4.z, a4.w};
            float bv[4] = {b4.x, b4.y, b4.z, b4.w};
            #pragma unroll
            for (int ri = 0; ri < 4; ++ri)
                #pragma unroll
                for (int oi = 0; oi < 4; ++oi)
                    acc[ri][oi] += av[ri] * bv[oi];
        }
    }

    float4 br = *(const float4*)(b_ro + o0 + 4 * tx);
    float brv[4] = {br.x, br.y, br.z, br.w};
    #pragma unroll
    for (int ri = 0; ri < 4; ++ri) {
        int row = row0 + 4 * ty + ri;
        int tt  = row >> 5;
        int bbx = row & 31;
        float4 v;
        v.x = acc[ri][0] + brv[0];
        v.y = acc[ri][1] + brv[1];
        v.z = acc[ri][2] + brv[2];
        v.w = acc[ri][3] + brv[3];
        *(float4*)(out + ((size_t)bbx * SEQ + tt) * ODIM + o0 + 4 * tx) = v;
    }
}

// ---------------------------------------------------------------------------
extern "C" void kernel_launch(void* const* d_in, const int* in_sizes, int n_in,
                              void* d_out, int out_size, void* d_ws, size_t ws_size,
                              hipStream_t stream) {
    const float* u    = (const float*)d_in[0];
    const float* s0   = (const float*)d_in[1];
    const float* Win  = (const float*)d_in[2];
    const float* W    = (const float*)d_in[3];
    const float* bias = (const float*)d_in[4];
    const float* w_ro = (const float*)d_in[5];
    const float* b_ro = (const float*)d_in[6];
    float* out = (float*)d_out;

    const size_t states_elems = (size_t)(SEQ + 1) * BATCH * RDIM;
    const size_t states_bytes = states_elems * sizeof(float);
    const size_t need = states_bytes + 512;
    if (ws_size < need) return;   // visible failure rather than OOB writes

    float* states = (float*)d_ws;
    unsigned* bar_cnt = (unsigned*)((char*)d_ws + states_bytes);
    unsigned* bar_sns = (unsigned*)((char*)d_ws + states_bytes + 128);

    esn_init<<<dim3(64), dim3(256), 0, stream>>>(s0, states, bar_cnt, bar_sns);

    void* args[] = { (void*)&u, (void*)&Win, (void*)&W, (void*)&bias,
                     (void*)&states, (void*)&bar_cnt, (void*)&bar_sns };
    hipLaunchCooperativeKernel((const void*)esn_scan,
                               dim3(SCAN_BLOCKS), dim3(SCAN_THREADS),
                               args, 0, stream);

    esn_readout<<<dim3((SEQ * BATCH / 64) * (ODIM / 64)), dim3(RO_THREADS), 0, stream>>>(
        states, w_ro, b_ro, out);
}